// Round 1
// baseline (564.526 us; speedup 1.0000x reference)
//
#include <hip/hip_runtime.h>
#include <hip/hip_bf16.h>

#define B_ 4
#define NQ_ 1024
#define NK_ 2048
#define DIM_ 512
#define CTX_ 1024
#define NH_ 8
#define HD_ 64
static constexpr float SCALE_ = 0.04419417382415922f; // 512^-0.5

typedef short bf16x8 __attribute__((ext_vector_type(8)));
typedef float f32x4 __attribute__((ext_vector_type(4)));

__device__ __forceinline__ unsigned f2u(float f) { union { float f; unsigned u; } v; v.f = f; return v.u; }

// pack 8 fp32 -> 8 bf16 (truncation) via v_perm: out[i] = high16(in[i])
__device__ __forceinline__ bf16x8 pack8(float4 lo, float4 hi) {
  union { unsigned u[4]; bf16x8 v; } r;
  r.u[0] = __builtin_amdgcn_perm(f2u(lo.y), f2u(lo.x), 0x07060302u);
  r.u[1] = __builtin_amdgcn_perm(f2u(lo.w), f2u(lo.z), 0x07060302u);
  r.u[2] = __builtin_amdgcn_perm(f2u(hi.y), f2u(hi.x), 0x07060302u);
  r.u[3] = __builtin_amdgcn_perm(f2u(hi.w), f2u(hi.z), 0x07060302u);
  return r.v;
}

__device__ __forceinline__ unsigned short f2bf_rne(float f) {
  unsigned u = f2u(f);
  u += 0x7fffu + ((u >> 16) & 1u);
  return (unsigned short)(u >> 16);
}

// ---------------------------------------------------------------------------
// Transpose + bf16-convert the three weight matrices: W [K,512] -> Wt [512,K]
// ---------------------------------------------------------------------------
__global__ __launch_bounds__(256) void transpose_w(
    const float* __restrict__ Wq, const float* __restrict__ Wk,
    const float* __restrict__ Wv, unsigned short* __restrict__ Wt) {
  int mat = blockIdx.z;
  const float* W; unsigned short* T; int K;
  if (mat == 0)      { W = Wq; T = Wt;                         K = DIM_; }
  else if (mat == 1) { W = Wk; T = Wt + DIM_*DIM_;             K = CTX_; }
  else               { W = Wv; T = Wt + DIM_*DIM_ + DIM_*CTX_; K = CTX_; }
  int k0 = blockIdx.x * 64;
  if (k0 >= K) return;
  int n0 = blockIdx.y * 64;
  __shared__ unsigned short tl[64][64]; // [n_local][k, chunk-XOR-swizzled]
  int tid = threadIdx.x;
  {
    int nb = (tid & 15) * 4;
    int rbase = tid >> 4;
    #pragma unroll
    for (int p = 0; p < 4; ++p) {
      int kr = rbase + p * 16;
      float4 v = *(const float4*)(W + (size_t)(k0 + kr) * DIM_ + n0 + nb);
      int ck = kr >> 3, ko = kr & 7;
      tl[nb + 0][((ck ^ ((nb + 0) & 7)) << 3) | ko] = (unsigned short)(f2u(v.x) >> 16);
      tl[nb + 1][((ck ^ ((nb + 1) & 7)) << 3) | ko] = (unsigned short)(f2u(v.y) >> 16);
      tl[nb + 2][((ck ^ ((nb + 2) & 7)) << 3) | ko] = (unsigned short)(f2u(v.z) >> 16);
      tl[nb + 3][((ck ^ ((nb + 3) & 7)) << 3) | ko] = (unsigned short)(f2u(v.w) >> 16);
    }
  }
  __syncthreads();
  {
    int nr = tid >> 2, cc = tid & 3;
    #pragma unroll
    for (int p = 0; p < 2; ++p) {
      int c = cc + p * 4;
      bf16x8 v = *(const bf16x8*)&tl[nr][(c ^ (nr & 7)) << 3];
      *(bf16x8*)(T + (size_t)(n0 + nr) * K + k0 + c * 8) = v;
    }
  }
}

// ---------------------------------------------------------------------------
// Projection GEMM: C[M,512] = A[M,K] @ W[K,512], A fp32, Wt = W^T bf16.
// 128x128 block tile, 4 waves (2x2), each wave 64x64 via 4x4 16x16x32 MFMAs.
// No LDS: A fragments read fp32 coalesced + packed; B fragments from Wt (L2).
// TRANS=1 writes V transposed as Vt[B][H][64][NK] for the PV B-operand.
// ---------------------------------------------------------------------------
template<int TRANS>
__global__ __launch_bounds__(256) void gemm_proj(
    const float* __restrict__ A, const unsigned short* __restrict__ Wt,
    unsigned short* __restrict__ C, int M, int K) {
  int tid = threadIdx.x, lane = tid & 63, wid = tid >> 6;
  int m0 = blockIdx.x * 128 + (wid >> 1) * 64;
  int n0 = blockIdx.y * 128 + (wid & 1) * 64;
  int rl = lane & 15, ch = (lane >> 4) * 8;
  const float* aptr = A + (size_t)(m0 + rl) * K + ch;
  const unsigned short* bptr = Wt + (size_t)(n0 + rl) * K + ch;
  f32x4 acc[4][4] = {};
  for (int k0 = 0; k0 < K; k0 += 32) {
    bf16x8 af[4], bfr[4];
    #pragma unroll
    for (int i = 0; i < 4; ++i) {
      const float* p = aptr + (size_t)i * 16 * K + k0;
      float4 lo = *(const float4*)p;
      float4 hi = *(const float4*)(p + 4);
      af[i] = pack8(lo, hi);
    }
    #pragma unroll
    for (int j = 0; j < 4; ++j)
      bfr[j] = *(const bf16x8*)(bptr + (size_t)j * 16 * K + k0);
    #pragma unroll
    for (int i = 0; i < 4; ++i)
      #pragma unroll
      for (int j = 0; j < 4; ++j)
        acc[i][j] = __builtin_amdgcn_mfma_f32_16x16x32_bf16(af[i], bfr[j], acc[i][j], 0, 0, 0);
  }
  int rq = (lane >> 4) * 4, cn = lane & 15;
  #pragma unroll
  for (int i = 0; i < 4; ++i)
    #pragma unroll
    for (int j = 0; j < 4; ++j)
      #pragma unroll
      for (int r = 0; r < 4; ++r) {
        int row = m0 + i * 16 + rq + r;
        int col = n0 + j * 16 + cn;
        unsigned short v = f2bf_rne(acc[i][j][r]);
        if (TRANS) {
          int b = row >> 11, k = row & 2047;   // M = 8192, 2048 rows per batch
          int h = col >> 6, d = col & 63;
          C[((size_t)(b * NH_ + h) * HD_ + d) * NK_ + k] = v;
        } else {
          C[(size_t)row * DIM_ + col] = v;
        }
      }
}

// ---------------------------------------------------------------------------
// Fused attention. Block = 4 waves; wave handles 16 q rows of one (b,h).
// Pass 1: QK^T MFMA -> per-row sum of exp (no max needed: |s| < ~3).
// Pass 2: recompute S, write normalized fp32 weights, P->bf16 via LDS,
//         PV MFMA with B-fragments from Vt (b128, L2-resident).
// ---------------------------------------------------------------------------
__global__ __launch_bounds__(256) void attn_fwd(
    const unsigned short* __restrict__ Qh, const unsigned short* __restrict__ Kh,
    const unsigned short* __restrict__ Vt, float* __restrict__ outO,
    float* __restrict__ outW) {
  int bid = blockIdx.x;
  int qt = bid & 15, h = (bid >> 4) & 7, b = bid >> 7;
  int tid = threadIdx.x, lane = tid & 63, wid = tid >> 6;
  int q0 = qt * 64 + wid * 16;
  int rl = lane & 15, ch = (lane >> 4) * 8, rq = (lane >> 4) * 4;
  __shared__ unsigned short Plds[4][16][40]; // +8 pad: 80B rows, 16B aligned

  const unsigned short* qbase = Qh + (size_t)(b * NQ_ + q0 + rl) * DIM_ + h * HD_;
  bf16x8 aq0 = *(const bf16x8*)(qbase + ch);
  bf16x8 aq1 = *(const bf16x8*)(qbase + 32 + ch);

  const unsigned short* kbase = Kh + (size_t)(b * NK_ + rl) * DIM_ + h * HD_;

  // ---- pass 1: denominators ----
  float ps[4] = {0.f, 0.f, 0.f, 0.f};
  #pragma unroll 4
  for (int kt = 0; kt < NK_ / 16; ++kt) {
    const unsigned short* kp = kbase + (size_t)kt * 16 * DIM_;
    bf16x8 bk0 = *(const bf16x8*)(kp + ch);
    bf16x8 bk1 = *(const bf16x8*)(kp + 32 + ch);
    f32x4 s = {};
    s = __builtin_amdgcn_mfma_f32_16x16x32_bf16(aq0, bk0, s, 0, 0, 0);
    s = __builtin_amdgcn_mfma_f32_16x16x32_bf16(aq1, bk1, s, 0, 0, 0);
    #pragma unroll
    for (int r = 0; r < 4; ++r) ps[r] += __expf(s[r] * SCALE_);
  }
  #pragma unroll
  for (int m = 1; m < 16; m <<= 1)
    #pragma unroll
    for (int r = 0; r < 4; ++r) ps[r] += __shfl_xor(ps[r], m);
  float inv[4];
  #pragma unroll
  for (int r = 0; r < 4; ++r) inv[r] = 1.0f / ps[r];

  // ---- pass 2: weights + PV ----
  f32x4 accO[4] = {};
  float* wbase = outW + (size_t)((b * NH_ + h) * NQ_ + q0 + rq) * NK_;
  for (int kc = 0; kc < NK_ / 32; ++kc) {
    #pragma unroll
    for (int t = 0; t < 2; ++t) {
      int kt = kc * 2 + t;
      const unsigned short* kp = kbase + (size_t)kt * 16 * DIM_;
      bf16x8 bk0 = *(const bf16x8*)(kp + ch);
      bf16x8 bk1 = *(const bf16x8*)(kp + 32 + ch);
      f32x4 s = {};
      s = __builtin_amdgcn_mfma_f32_16x16x32_bf16(aq0, bk0, s, 0, 0, 0);
      s = __builtin_amdgcn_mfma_f32_16x16x32_bf16(aq1, bk1, s, 0, 0, 0);
      #pragma unroll
      for (int r = 0; r < 4; ++r) {
        float p = __expf(s[r] * SCALE_) * inv[r];
        wbase[(size_t)r * NK_ + kt * 16 + rl] = p;
        Plds[wid][rq + r][t * 16 + rl] = (unsigned short)(f2u(p) >> 16);
      }
    }
    bf16x8 ap = *(const bf16x8*)&Plds[wid][rl][ch];
    #pragma unroll
    for (int dt = 0; dt < 4; ++dt) {
      const unsigned short* vp =
          Vt + ((size_t)(b * NH_ + h) * HD_ + dt * 16 + rl) * NK_ + kc * 32 + ch;
      bf16x8 bv = *(const bf16x8*)vp;
      accO[dt] = __builtin_amdgcn_mfma_f32_16x16x32_bf16(ap, bv, accO[dt], 0, 0, 0);
    }
  }
  float* obase = outO + (size_t)(b * NQ_ + q0 + rq) * DIM_ + h * HD_;
  #pragma unroll
  for (int dt = 0; dt < 4; ++dt)
    #pragma unroll
    for (int r = 0; r < 4; ++r)
      obase[(size_t)r * DIM_ + dt * 16 + rl] = accO[dt][r];
}

extern "C" void kernel_launch(void* const* d_in, const int* in_sizes, int n_in,
                              void* d_out, int out_size, void* d_ws, size_t ws_size,
                              hipStream_t stream) {
  (void)in_sizes; (void)n_in; (void)out_size; (void)ws_size;
  const float* q   = (const float*)d_in[0];
  const float* ctx = (const float*)d_in[1];
  const float* Wq  = (const float*)d_in[2];
  const float* Wk  = (const float*)d_in[3];
  const float* Wv  = (const float*)d_in[4];

  unsigned short* Wt = (unsigned short*)d_ws;              // 1,310,720 elems
  unsigned short* Qh = Wt + 1310720;                       // 2,097,152
  unsigned short* Kh = Qh + 2097152;                       // 4,194,304
  unsigned short* Vt = Kh + 4194304;                       // 4,194,304
  float* outO = (float*)d_out;                             // [4,1024,512]
  float* outW = outO + (size_t)B_ * NQ_ * DIM_;            // [4,8,1024,2048]

  transpose_w<<<dim3(16, 8, 3), 256, 0, stream>>>(Wq, Wk, Wv, Wt);
  gemm_proj<0><<<dim3(32, 4), 256, 0, stream>>>(q,   Wt,                  Qh, 4096, DIM_);
  gemm_proj<0><<<dim3(64, 4), 256, 0, stream>>>(ctx, Wt + 262144,         Kh, 8192, CTX_);
  gemm_proj<1><<<dim3(64, 4), 256, 0, stream>>>(ctx, Wt + 262144 + 524288, Vt, 8192, CTX_);
  attn_fwd<<<dim3(512), 256, 0, stream>>>(Qh, Kh, Vt, outO, outW);
}